// Round 6
// baseline (4027.566 us; speedup 1.0000x reference)
//
#include <hip/hip_runtime.h>
#include <string.h>

// LSTM_13159779795583 : 2-layer LSTM (B=32,T=512,IN=256,H=1024) + FC(1024->256)
//
// Round 6: sentinel dataflow + cheap probe + wide parallel coherent loads.
//  - probe phase: 1x8B sc0 load per lane covers all 64 producer chunks of the
//    wave's K-slice; poll until all chunks have first unit -> detect latency
//    and poll traffic collapse (512B vs 16KB per poll).
//  - load phase: 32 A-frags as 2 groups x 16 loads, ONE vmcnt(0) per group
//    (was 4 groups x 8): serialized L3 round-trips 4 -> 2.
//  - full NaN validation + whole-group retry kept (probe is heuristic only;
//    correctness still rests on atomic 8B units + NaN sentinel).
//  - everything else as round 5 (write-once h slots, deepened L1 pipeline,
//    cells on x-waves, one __syncthreads/step, LDS stage dbuf).

#define T_STEPS 512
#define BATCH   32
#define IN_DIM  256
#define HID     1024
#define OUT_DIM 256
#define NWG     128
#define TPB     512
#define UNITS   8               // hidden units per WG per layer
#define CH      (BATCH * UNITS) // fp16 per h-chunk (256 = 512B)
#define NSTEP   514             // s = 0..513 (L0: t=s, L1: t=s-2)

typedef _Float16 half8  __attribute__((ext_vector_type(8)));
typedef float    f32x16 __attribute__((ext_vector_type(16)));
typedef int      v4i    __attribute__((ext_vector_type(4)));

__device__ __forceinline__ float sigm(float x)      { return 1.f / (1.f + __expf(-x)); }
__device__ __forceinline__ float tanh_fast(float x) { return 2.f / (1.f + __expf(-2.f * x)) - 1.f; }

#define ATOMIC_ST8(p, v) __hip_atomic_store((p), (v), __ATOMIC_RELAXED, __HIP_MEMORY_SCOPE_AGENT)

// one coherent 8B probe (bypass L1/L2)
__device__ __forceinline__ unsigned long long probe8(const char* p) {
    unsigned long long v;
    asm volatile("global_load_dwordx2 %0, %1, off sc0 sc1\n\t"
                 "s_waitcnt vmcnt(0)"
                 : "=v"(v) : "v"(p) : "memory");
    return v;
}

// 16 coherent 16B loads (frag stride 1024B), ONE vmcnt(0) at the end.
__device__ __forceinline__ void ld16_coherent(const char* b0, v4i* F) {
    asm volatile(
        "global_load_dwordx4 %0, %16, off sc0 sc1\n\t"
        "global_load_dwordx4 %1, %16, off offset:1024 sc0 sc1\n\t"
        "global_load_dwordx4 %2, %16, off offset:2048 sc0 sc1\n\t"
        "global_load_dwordx4 %3, %16, off offset:3072 sc0 sc1\n\t"
        "global_load_dwordx4 %4, %17, off sc0 sc1\n\t"
        "global_load_dwordx4 %5, %17, off offset:1024 sc0 sc1\n\t"
        "global_load_dwordx4 %6, %17, off offset:2048 sc0 sc1\n\t"
        "global_load_dwordx4 %7, %17, off offset:3072 sc0 sc1\n\t"
        "global_load_dwordx4 %8, %18, off sc0 sc1\n\t"
        "global_load_dwordx4 %9, %18, off offset:1024 sc0 sc1\n\t"
        "global_load_dwordx4 %10, %18, off offset:2048 sc0 sc1\n\t"
        "global_load_dwordx4 %11, %18, off offset:3072 sc0 sc1\n\t"
        "global_load_dwordx4 %12, %19, off sc0 sc1\n\t"
        "global_load_dwordx4 %13, %19, off offset:1024 sc0 sc1\n\t"
        "global_load_dwordx4 %14, %19, off offset:2048 sc0 sc1\n\t"
        "global_load_dwordx4 %15, %19, off offset:3072 sc0 sc1\n\t"
        "s_waitcnt vmcnt(0)"
        : "=&v"(F[0]), "=&v"(F[1]), "=&v"(F[2]),  "=&v"(F[3]),
          "=&v"(F[4]), "=&v"(F[5]), "=&v"(F[6]),  "=&v"(F[7]),
          "=&v"(F[8]), "=&v"(F[9]), "=&v"(F[10]), "=&v"(F[11]),
          "=&v"(F[12]), "=&v"(F[13]), "=&v"(F[14]), "=&v"(F[15])
        : "v"(b0), "v"(b0 + 4096), "v"(b0 + 8192), "v"(b0 + 12288)
        : "memory");
}

// producer stores 8B units atomically; check low u16 of each 8B half
__device__ __forceinline__ bool frag_ok(v4i f) {
    return ((f.x & 0xffff) != 0x7E7E) & ((f.z & 0xffff) != 0x7E7E);
}

__global__ __launch_bounds__(TPB, 2) void lstm_persist(
    const float* __restrict__ W_ih0, const float* __restrict__ W_hh0,
    const float* __restrict__ b_ih0, const float* __restrict__ b_hh0,
    const float* __restrict__ W_ih1, const float* __restrict__ W_hh1,
    const float* __restrict__ b_ih1, const float* __restrict__ b_hh1,
    const _Float16* __restrict__ xb,
    _Float16* __restrict__ h0a, _Float16* __restrict__ h1a)
{
    __shared__ float stage[2][8][BATCH][33];  // double-buffered, padded
    __shared__ float cst[2][BATCH][UNITS];    // cell state, both layers
    __shared__ float biasS[2][32];            // b_ih + b_hh, this WG's rows

    const int tid  = threadIdx.x;
    const int w    = tid >> 6;        // wave id 0..7
    const int lane = tid & 63;
    const int rho  = lane & 31;       // MFMA A m-row (batch)
    const int kg   = (lane >> 5) << 3;// k sub-offset (0 or 8)
    const int blk  = blockIdx.x;

    // wave roles: matrix 0=W_hh0 1=W_ih0 2=W_ih1 3=W_hh1 ; K-range split
    const int matv[8]   = {0, 0,   1, 2, 2,   3, 3,   1};
    const int kbasev[8] = {0, 512, 0, 0, 512, 0, 512, 128};
    const int nkv[8]    = {32, 32, 8, 32, 32, 32, 32, 8};
    const int mat   = matv[w];
    const int kbase = kbasev[w];
    const int nk    = nkv[w];

    const float* wptr; int rowlen;
    if      (mat == 0) { wptr = W_hh0; rowlen = HID;    }
    else if (mat == 1) { wptr = W_ih0; rowlen = IN_DIM; }
    else if (mat == 2) { wptr = W_ih1; rowlen = HID;    }
    else               { wptr = W_hh1; rowlen = HID;    }

    // this lane's weight row: gate = rho>>3, unit = blk*8 + (rho&7)
    const int grow = (rho >> 3) * HID + blk * UNITS + (rho & 7);

    // ---- load + pack B fragments into registers (fp32 -> fp16), once ----
    half8 B[32];
    #pragma unroll
    for (int kk = 0; kk < 32; ++kk) {
        half8 bf;
        if (kk < nk) {
            const float* p = wptr + (size_t)grow * rowlen + kbase + kk * 16 + kg;
            float4 lo = *(const float4*)p;
            float4 hi = *(const float4*)(p + 4);
            bf[0] = (_Float16)lo.x; bf[1] = (_Float16)lo.y;
            bf[2] = (_Float16)lo.z; bf[3] = (_Float16)lo.w;
            bf[4] = (_Float16)hi.x; bf[5] = (_Float16)hi.y;
            bf[6] = (_Float16)hi.z; bf[7] = (_Float16)hi.w;
        } else {
            #pragma unroll
            for (int j = 0; j < 8; ++j) bf[j] = (_Float16)0.f;
        }
        B[kk] = bf;
    }

    // ---- init: biases, cell state ----
    if (tid < 64) {
        int L = tid >> 5, n = tid & 31;
        int gr = (n >> 3) * HID + blk * UNITS + (n & 7);
        biasS[L][n] = L ? (b_ih1[gr] + b_hh1[gr]) : (b_ih0[gr] + b_hh0[gr]);
    }
    ((float*)cst)[tid] = 0.f;  // 512 floats, one per thread
    __syncthreads();
    // (h slots: NaN-filled + slot0/slot1 zeroed by host-side memsets)

    // ---- cell helper: one wave handles one layer (4 units/lane) ----
    auto docell = [&](int L, int sb, _Float16* dst) {
        const int b  = lane >> 1;
        const int u0 = (lane & 1) * 4;
        _Float16 hh[4];
        #pragma unroll
        for (int j = 0; j < 4; ++j) {
            const int u = u0 + j;
            float pre[4];
            #pragma unroll
            for (int g = 0; g < 4; ++g) {
                const int n = g * 8 + u;
                float v = biasS[L][n];
                if (L == 0)
                    v += stage[sb][0][b][n] + stage[sb][1][b][n]
                       + stage[sb][2][b][n] + stage[sb][7][b][n];
                else
                    v += stage[sb][3][b][n] + stage[sb][4][b][n]
                       + stage[sb][5][b][n] + stage[sb][6][b][n];
                pre[g] = v;
            }
            float iv = sigm(pre[0]);
            float fv = sigm(pre[1]);
            float gv = tanh_fast(pre[2]);
            float ov = sigm(pre[3]);
            float c  = fv * cst[L][b][u] + iv * gv;
            cst[L][b][u] = c;
            hh[j] = (_Float16)(ov * tanh_fast(c));
        }
        unsigned long long pk;
        memcpy(&pk, hh, 8);
        // fire-and-forget WT store; consumers detect via non-NaN data
        ATOMIC_ST8((unsigned long long*)(dst + b * UNITS + u0), pk);
    };

    // ---- main loop: s=0..513; L0: t=s (s<512), L1: t=s-2 (s>=2) ----
    for (int s = 0; s < NSTEP; ++s) {
        const int  sb  = s & 1;
        const bool act = (mat <= 1) ? (s < T_STEPS) : (s >= 2);
        if (act) {
            const int cbase = (kbase >> 3) + (kg >> 3);
            f32x16 acc0, acc1;
            #pragma unroll
            for (int r = 0; r < 16; ++r) { acc0[r] = 0.f; acc1[r] = 0.f; }

            if (mat == 0 || mat == 3) {
                // fresh recurrent h: probe, then 2 wide coherent load groups
                const _Float16* slotb = (mat == 0)
                    ? h0a + (size_t)s * NWG * CH
                    : h1a + (size_t)(s - 1) * NWG * CH;
                const int cbase0 = kbase >> 3;   // 0 or 64
                // probe: lane covers chunk cbase0+lane (64 chunks/wave)
                const char* pp = (const char*)(slotb + (size_t)(cbase0 + lane) * CH);
                while (!__all((probe8(pp) & 0xffff) != 0x7E7E)) {}

                const char* base = (const char*)(slotb + (size_t)cbase * CH
                                                 + (size_t)rho * UNITS);
                #pragma unroll
                for (int g = 0; g < 2; ++g) {
                    v4i F[16];
                    for (;;) {
                        ld16_coherent(base + g * 16384, F);
                        bool ok = true;
                        #pragma unroll
                        for (int j = 0; j < 16; ++j) ok &= frag_ok(F[j]);
                        if (__all(ok)) break;
                    }
                    #pragma unroll
                    for (int j = 0; j < 16; ++j) {
                        half8 a = __builtin_bit_cast(half8, F[j]);
                        if (j & 1) acc1 = __builtin_amdgcn_mfma_f32_32x32x16_f16(a, B[g * 16 + j], acc1, 0, 0, 0);
                        else       acc0 = __builtin_amdgcn_mfma_f32_32x32x16_f16(a, B[g * 16 + j], acc0, 0, 0, 0);
                    }
                }
            } else {
                // verified-or-static data: plain cacheable loads
                const _Float16* src = (mat == 1)
                    ? xb  + ((size_t)s * 32 + cbase) * CH
                    : h0a + ((size_t)(s - 1) * NWG + cbase) * CH;
                const _Float16* ap = src + rho * UNITS;
                #pragma unroll
                for (int kk = 0; kk < 32; kk += 2) {
                    if (kk < nk) {
                        half8 a = *(const half8*)(ap + (size_t)kk * 2 * CH);
                        acc0 = __builtin_amdgcn_mfma_f32_32x32x16_f16(a, B[kk], acc0, 0, 0, 0);
                    }
                    if (kk + 1 < nk) {
                        half8 a = *(const half8*)(ap + (size_t)(kk + 1) * 2 * CH);
                        acc1 = __builtin_amdgcn_mfma_f32_32x32x16_f16(a, B[kk + 1], acc1, 0, 0, 0);
                    }
                }
            }
            // C/D layout: n = lane&31, m = (r&3)+8*(r>>2)+4*(lane>>5)
            #pragma unroll
            for (int r = 0; r < 16; ++r) {
                int m = (r & 3) + ((r >> 2) << 3) + ((lane >> 5) << 2);
                stage[sb][w][m][rho] = acc0[r] + acc1[r];
            }
        }
        __syncthreads();   // stage complete; next step uses stage[1-sb]

        if (w == 2 && s < T_STEPS)  // L0 cell for t=s -> h0a slot s+1
            docell(0, sb, h0a + ((size_t)(s + 1) * NWG + blk) * CH);
        if (w == 7 && s >= 2)       // L1 cell for t=s-2 -> h1a slot s
            docell(1, sb, h1a + ((size_t)s * NWG + blk) * CH);
    }
}

// ---- epilogue FC: out[b][t][o] = sum_h h1[t][b][h]*fc_w[o][h] + fc_b[o] ----
// h1[t] lives in h1a slot t+2.
__global__ __launch_bounds__(256) void fc_kern(
    const _Float16* __restrict__ h1a, const _Float16* __restrict__ fcwb,
    const float* __restrict__ fc_b, float* __restrict__ out)
{
    const int wv   = threadIdx.x >> 6;
    const int lane = threadIdx.x & 63;
    const int t    = blockIdx.x * 4 + wv;   // grid 128 -> t = 0..511
    const int kg   = (lane >> 5) << 3;
    const _Float16* ab = h1a + (((size_t)(t + 2) * NWG) + (kg >> 3)) * CH
                             + (size_t)(lane & 31) * UNITS;

    #pragma unroll 1
    for (int nt = 0; nt < 8; ++nt) {
        const _Float16* bb = fcwb + (size_t)(nt * 32 + (lane & 31)) * HID + kg;
        f32x16 acc0, acc1;
        #pragma unroll
        for (int r = 0; r < 16; ++r) { acc0[r] = 0.f; acc1[r] = 0.f; }
        #pragma unroll
        for (int kk = 0; kk < 64; kk += 2) {
            half8 a0 = *(const half8*)(ab + (size_t)kk * 2 * CH);
            half8 b0 = *(const half8*)(bb + kk * 16);
            acc0 = __builtin_amdgcn_mfma_f32_32x32x16_f16(a0, b0, acc0, 0, 0, 0);
            half8 a1 = *(const half8*)(ab + (size_t)(kk + 1) * 2 * CH);
            half8 b1 = *(const half8*)(bb + (kk + 1) * 16);
            acc1 = __builtin_amdgcn_mfma_f32_32x32x16_f16(a1, b1, acc1, 0, 0, 0);
        }
        const int o = nt * 32 + (lane & 31);
        const float bias = fc_b[o];
        #pragma unroll
        for (int r = 0; r < 16; ++r) {
            int m = (r & 3) + ((r >> 2) << 3) + ((lane >> 5) << 2);  // batch b
            out[(size_t)m * (T_STEPS * OUT_DIM) + (size_t)t * OUT_DIM + o]
                = acc0[r] + acc1[r] + bias;
        }
    }
}

// ---- pre-cast x (-> [t][chunk][b][8] fp16) and fc_w (-> fp16) ----
__global__ __launch_bounds__(256) void precast(
    const float* __restrict__ x, const float* __restrict__ fcw,
    _Float16* __restrict__ xb, _Float16* __restrict__ fcwb)
{
    const int idx = blockIdx.x * 256 + threadIdx.x;
    const int N1 = T_STEPS * BATCH * IN_DIM / 4;  // 1048576
    const int N2 = OUT_DIM * HID / 4;             // 65536
    if (idx < N1) {
        int e = idx << 2;
        int d = e & (IN_DIM - 1);
        int bt = e >> 8;
        int b = bt & 31;
        int t = bt >> 5;
        float4 v = *(const float4*)(x + ((size_t)b * T_STEPS + t) * IN_DIM + d);
        _Float16* dst = xb + (((size_t)t * 32 + (d >> 3)) * 32 + b) * 8 + (d & 7);
        dst[0] = (_Float16)v.x; dst[1] = (_Float16)v.y;
        dst[2] = (_Float16)v.z; dst[3] = (_Float16)v.w;
    } else if (idx < N1 + N2) {
        int e = (idx - N1) << 2;
        float4 v = *(const float4*)(fcw + e);
        _Float16* dst = fcwb + e;
        dst[0] = (_Float16)v.x; dst[1] = (_Float16)v.y;
        dst[2] = (_Float16)v.z; dst[3] = (_Float16)v.w;
    }
}

extern "C" void kernel_launch(void* const* d_in, const int* in_sizes, int n_in,
                              void* d_out, int out_size, void* d_ws, size_t ws_size,
                              hipStream_t stream) {
    const float* x     = (const float*)d_in[0];
    const float* W_ih0 = (const float*)d_in[1];
    const float* W_hh0 = (const float*)d_in[2];
    const float* b_ih0 = (const float*)d_in[3];
    const float* b_hh0 = (const float*)d_in[4];
    const float* W_ih1 = (const float*)d_in[5];
    const float* W_hh1 = (const float*)d_in[6];
    const float* b_ih1 = (const float*)d_in[7];
    const float* b_hh1 = (const float*)d_in[8];
    const float* fc_w  = (const float*)d_in[9];
    const float* fc_b  = (const float*)d_in[10];
    float* out = (float*)d_out;

    const size_t SLOT = (size_t)NWG * CH;          // fp16 per slot (32768)
    char* ws = (char*)d_ws;
    size_t off = 0;
    _Float16* xb   = (_Float16*)(ws + off); off += (size_t)T_STEPS * BATCH * IN_DIM * 2;
    _Float16* h0a  = (_Float16*)(ws + off); off += (size_t)513 * SLOT * 2;
    _Float16* h1a  = (_Float16*)(ws + off); off += (size_t)515 * SLOT * 2;
    _Float16* fcwb = (_Float16*)(ws + off); off += (size_t)OUT_DIM * HID * 2;
    // total ws use ~76 MB

    // NaN-sentinel fill (0x7E7E = fp16 NaN), then zero the initial-state slots
    hipMemsetAsync(h0a, 0x7E, 513 * SLOT * 2, stream);
    hipMemsetAsync(h1a, 0x7E, 515 * SLOT * 2, stream);
    hipMemsetAsync(h0a, 0, SLOT * 2, stream);            // h0 slot 0 = h0[-1] = 0
    hipMemsetAsync(h1a + SLOT, 0, SLOT * 2, stream);     // h1 slot 1 = h1[-1] = 0
    precast<<<4352, 256, 0, stream>>>(x, fc_w, xb, fcwb);
    lstm_persist<<<NWG, TPB, 0, stream>>>(W_ih0, W_hh0, b_ih0, b_hh0,
                                          W_ih1, W_hh1, b_ih1, b_hh1,
                                          xb, h0a, h1a);
    fc_kern<<<128, 256, 0, stream>>>(h1a, fcwb, fc_b, out);
}

// Round 7
// 2222.933 us; speedup vs baseline: 1.8118x; 1.8118x over previous
//
#include <hip/hip_runtime.h>
#include <string.h>

// LSTM_13159779795583 : 2-layer LSTM (B=32,T=512,IN=256,H=1024) + FC(1024->256)
//
// Round 7: layer-split WGs + publish-at-iteration-head.
//  - 128 WGs: blk<64 -> layer0 (16 units each), blk>=64 -> layer1.
//  - per WG: waves 0-3 = W_hh (K-quarters, full 64 gate rows via 2 MFMAs/frag)
//    + cell duty at iteration head; waves 4-7 = W_ih quarters.
//  - cell runs FIRST after sync (reads prev-iter stage from LDS, no remote
//    wait), publishes h chunk via 4B WT stores -> recurrence critical path =
//    cell -> propagate -> detect+load -> MFMA -> sync.
//  - L1 trails L0 by one iteration (xw1 reads h0 slot i-1): plain cacheable
//    loads w/ NaN check + coherent fallback. hh waves: probe + 2x8 coherent
//    load groups with full NaN validation (4B producer units).
//  - h layout [slot][wg64][b32][u16] (chunk = 1KB contiguous per producer).

#define T_STEPS 512
#define BATCH   32
#define IN_DIM  256
#define HID     1024
#define OUT_DIM 256
#define NWGL    64              // WGs per layer
#define TPB     512
#define U       16              // hidden units per WG
#define CHW     (BATCH * U)     // fp16 per chunk (512 = 1KB)
#define SLOTE   (NWGL * CHW)    // fp16 per slot (32768 = 64KB)
#define NITER   515             // i = 0..514

typedef _Float16 half8  __attribute__((ext_vector_type(8)));
typedef float    f32x16 __attribute__((ext_vector_type(16)));
typedef int      v4i    __attribute__((ext_vector_type(4)));

__device__ __forceinline__ float sigm(float x)      { return 1.f / (1.f + __expf(-x)); }
__device__ __forceinline__ float tanh_fast(float x) { return 2.f / (1.f + __expf(-2.f * x)) - 1.f; }

#define ATOMIC_ST4(p, v) __hip_atomic_store((p), (v), __ATOMIC_RELAXED, __HIP_MEMORY_SCOPE_AGENT)

__device__ __forceinline__ unsigned probe4(const char* p) {
    unsigned v;
    asm volatile("global_load_dword %0, %1, off sc0 sc1\n\t"
                 "s_waitcnt vmcnt(0)" : "=v"(v) : "v"(p) : "memory");
    return v;
}

// 8 coherent 16B loads (frag stride 1024B), one vmcnt(0)
__device__ __forceinline__ void ld8_coherent(const char* b0, v4i* F) {
    asm volatile(
        "global_load_dwordx4 %0, %8, off sc0 sc1\n\t"
        "global_load_dwordx4 %1, %8, off offset:1024 sc0 sc1\n\t"
        "global_load_dwordx4 %2, %8, off offset:2048 sc0 sc1\n\t"
        "global_load_dwordx4 %3, %8, off offset:3072 sc0 sc1\n\t"
        "global_load_dwordx4 %4, %9, off sc0 sc1\n\t"
        "global_load_dwordx4 %5, %9, off offset:1024 sc0 sc1\n\t"
        "global_load_dwordx4 %6, %9, off offset:2048 sc0 sc1\n\t"
        "global_load_dwordx4 %7, %9, off offset:3072 sc0 sc1\n\t"
        "s_waitcnt vmcnt(0)"
        : "=&v"(F[0]), "=&v"(F[1]), "=&v"(F[2]), "=&v"(F[3]),
          "=&v"(F[4]), "=&v"(F[5]), "=&v"(F[6]), "=&v"(F[7])
        : "v"(b0), "v"(b0 + 4096)
        : "memory");
}

// producers store 4B units (2 fp16); check low u16 of every dword
__device__ __forceinline__ bool frag_ok4(v4i f) {
    return ((f.x & 0xffff) != 0x7E7E) & ((f.y & 0xffff) != 0x7E7E)
         & ((f.z & 0xffff) != 0x7E7E) & ((f.w & 0xffff) != 0x7E7E);
}

__global__ __launch_bounds__(TPB, 2) void lstm_persist(
    const float* __restrict__ W_ih0, const float* __restrict__ W_hh0,
    const float* __restrict__ b_ih0, const float* __restrict__ b_hh0,
    const float* __restrict__ W_ih1, const float* __restrict__ W_hh1,
    const float* __restrict__ b_ih1, const float* __restrict__ b_hh1,
    const _Float16* __restrict__ xb,
    _Float16* __restrict__ h0a, _Float16* __restrict__ h1a)
{
    __shared__ float stage[2][8][BATCH][65];  // [buf][wave][b][nn0..63 +pad]
    __shared__ float cst[BATCH][U];           // this WG's layer cell state
    __shared__ float biasS[64];               // b_ih+b_hh, 64 gate rows

    const int tid  = threadIdx.x;
    const int w    = tid >> 6;
    const int lane = tid & 63;
    const int rho  = lane & 31;
    const int kg   = (lane >> 5) << 3;   // 0 or 8
    const int blk  = blockIdx.x;
    const int isL1 = blk >= NWGL;
    const int be   = blk & (NWGL - 1);
    const bool isHH = (w < 4);

    const float* wptr; int kbase, nf, rowlen;
    if (isHH)      { wptr = isL1 ? W_hh1 : W_hh0; kbase = w * 256;       nf = 16; rowlen = HID;    }
    else if (isL1) { wptr = W_ih1;                kbase = (w - 4) * 256; nf = 16; rowlen = HID;    }
    else           { wptr = W_ih0;                kbase = (w - 4) * 64;  nf = 4;  rowlen = IN_DIM; }

    // ---- B fragments (fp32 -> fp16), once. Bf[kf][nh], nn = nh*32+rho ----
    half8 Bf[16][2];
    #pragma unroll
    for (int kf = 0; kf < 16; ++kf)
        #pragma unroll
        for (int nh = 0; nh < 2; ++nh) {
            half8 bf;
            if (kf < nf) {
                const int nn = nh * 32 + rho;
                const int row = (nn >> 4) * HID + be * U + (nn & 15);
                const float* p = wptr + (size_t)row * rowlen + kbase + kf * 16 + kg;
                float4 lo = *(const float4*)p;
                float4 hi = *(const float4*)(p + 4);
                bf[0] = (_Float16)lo.x; bf[1] = (_Float16)lo.y;
                bf[2] = (_Float16)lo.z; bf[3] = (_Float16)lo.w;
                bf[4] = (_Float16)hi.x; bf[5] = (_Float16)hi.y;
                bf[6] = (_Float16)hi.z; bf[7] = (_Float16)hi.w;
            } else {
                #pragma unroll
                for (int j = 0; j < 8; ++j) bf[j] = (_Float16)0.f;
            }
            Bf[kf][nh] = bf;
        }

    // ---- init ----
    if (tid < 64) {
        const int row = (tid >> 4) * HID + be * U + (tid & 15);
        biasS[tid] = isL1 ? (b_ih1[row] + b_hh1[row]) : (b_ih0[row] + b_hh0[row]);
    }
    ((float*)cst)[tid] = 0.f;
    __syncthreads();

    _Float16* hout = isL1 ? h1a : h0a;
    const _Float16* hin = isL1 ? h1a : h0a;

    #pragma unroll 1
    for (int i = 0; i < NITER; ++i) {
        const int sb = i & 1;

        // ---- cell at iteration HEAD (hh waves), publish h slot i ----
        const bool cell_act = isL1 ? (i >= 3 && i <= 514) : (i >= 1 && i <= 512);
        if (isHH && cell_act) {
            const int sbp = (i - 1) & 1;
            const int cid = w * 128 + lane * 2;
            const int b = cid >> 4, u0 = cid & 15;
            _Float16 h2[2];
            #pragma unroll
            for (int j = 0; j < 2; ++j) {
                const int u = u0 + j;
                float pre[4];
                #pragma unroll
                for (int g = 0; g < 4; ++g) {
                    const int n = g * 16 + u;
                    float v = biasS[n];
                    #pragma unroll
                    for (int p = 0; p < 8; ++p) v += stage[sbp][p][b][n];
                    pre[g] = v;
                }
                float iv = sigm(pre[0]);
                float fv = sigm(pre[1]);
                float gv = tanh_fast(pre[2]);
                float ov = sigm(pre[3]);
                float c  = fv * cst[b][u] + iv * gv;
                cst[b][u] = c;
                h2[j] = (_Float16)(ov * tanh_fast(c));
            }
            unsigned pk;
            memcpy(&pk, h2, 4);
            ATOMIC_ST4((unsigned*)(hout + (size_t)i * SLOTE + be * CHW + b * U + u0), pk);
        }

        // ---- compute ----
        const bool comp_act = isL1 ? (i >= 2 && i < 2 + T_STEPS) : (i < T_STEPS);
        if (comp_act) {
            f32x16 acc0, acc1;
            #pragma unroll
            for (int r = 0; r < 16; ++r) { acc0[r] = 0.f; acc1[r] = 0.f; }

            if (isHH) {
                const _Float16* slotb = hin + (size_t)i * SLOTE;
                // probe first 4B of each of this wave's 16 producer chunks
                const char* pp = (const char*)(slotb + (size_t)(w * 16 + (lane & 15)) * CHW);
                while (!__all((probe4(pp) & 0xffffu) != 0x7E7Eu)) {}
                const _Float16* ap = slotb + (size_t)(w * 16) * CHW + rho * U + kg;
                #pragma unroll
                for (int g = 0; g < 2; ++g) {
                    v4i F[8];
                    for (;;) {
                        ld8_coherent((const char*)(ap + g * 8 * CHW), F);
                        bool ok = true;
                        #pragma unroll
                        for (int j = 0; j < 8; ++j) ok &= frag_ok4(F[j]);
                        if (__all(ok)) break;
                    }
                    #pragma unroll
                    for (int j = 0; j < 8; ++j) {
                        half8 a = __builtin_bit_cast(half8, F[j]);
                        acc0 = __builtin_amdgcn_mfma_f32_32x32x16_f16(a, Bf[g * 8 + j][0], acc0, 0, 0, 0);
                        acc1 = __builtin_amdgcn_mfma_f32_32x32x16_f16(a, Bf[g * 8 + j][1], acc1, 0, 0, 0);
                    }
                }
            } else if (isL1) {
                // xw1: h0 slot i-1 (one iter slack): cacheable fast path + fallback
                const _Float16* ap = h0a + (size_t)(i - 1) * SLOTE
                                   + (size_t)((w - 4) * 16) * CHW + rho * U + kg;
                #pragma unroll
                for (int g = 0; g < 2; ++g) {
                    v4i F[8];
                    bool ok = true;
                    #pragma unroll
                    for (int j = 0; j < 8; ++j) {
                        F[j] = *(const v4i*)(ap + (size_t)(g * 8 + j) * CHW);
                        ok &= frag_ok4(F[j]);
                    }
                    if (!__all(ok)) {
                        for (;;) {
                            ld8_coherent((const char*)(ap + g * 8 * CHW), F);
                            bool ok2 = true;
                            #pragma unroll
                            for (int j = 0; j < 8; ++j) ok2 &= frag_ok4(F[j]);
                            if (__all(ok2)) break;
                        }
                    }
                    #pragma unroll
                    for (int j = 0; j < 8; ++j) {
                        half8 a = __builtin_bit_cast(half8, F[j]);
                        acc0 = __builtin_amdgcn_mfma_f32_32x32x16_f16(a, Bf[g * 8 + j][0], acc0, 0, 0, 0);
                        acc1 = __builtin_amdgcn_mfma_f32_32x32x16_f16(a, Bf[g * 8 + j][1], acc1, 0, 0, 0);
                    }
                }
            } else {
                // xw0: static x, 4 frags
                const _Float16* ap = xb + ((size_t)i * 16 + (w - 4) * 4) * CHW + rho * U + kg;
                #pragma unroll
                for (int j = 0; j < 4; ++j) {
                    half8 a = *(const half8*)(ap + (size_t)j * CHW);
                    acc0 = __builtin_amdgcn_mfma_f32_32x32x16_f16(a, Bf[j][0], acc0, 0, 0, 0);
                    acc1 = __builtin_amdgcn_mfma_f32_32x32x16_f16(a, Bf[j][1], acc1, 0, 0, 0);
                }
            }
            // C/D: n = lane&31, b = (r&3)+8*(r>>2)+4*(lane>>5)
            #pragma unroll
            for (int r = 0; r < 16; ++r) {
                const int b = (r & 3) + ((r >> 2) << 3) + ((lane >> 5) << 2);
                stage[sb][w][b][rho]      = acc0[r];
                stage[sb][w][b][32 + rho] = acc1[r];
            }
        }
        __syncthreads();
    }
}

// ---- epilogue FC: h1[t] = slot t+3, layout [slot][wg][b][u16] ----
__global__ __launch_bounds__(256) void fc_kern(
    const _Float16* __restrict__ h1a, const _Float16* __restrict__ fcwb,
    const float* __restrict__ fc_b, float* __restrict__ out)
{
    const int wv   = threadIdx.x >> 6;
    const int lane = threadIdx.x & 63;
    const int t    = blockIdx.x * 4 + wv;
    const int kg   = (lane >> 5) << 3;
    const _Float16* ab = h1a + (size_t)(t + 3) * SLOTE + (size_t)(lane & 31) * U + kg;

    #pragma unroll 1
    for (int nt = 0; nt < 8; ++nt) {
        const _Float16* bb = fcwb + (size_t)(nt * 32 + (lane & 31)) * HID + kg;
        f32x16 acc0, acc1;
        #pragma unroll
        for (int r = 0; r < 16; ++r) { acc0[r] = 0.f; acc1[r] = 0.f; }
        #pragma unroll
        for (int kk = 0; kk < 64; kk += 2) {
            half8 a0 = *(const half8*)(ab + (size_t)kk * CHW);
            half8 b0 = *(const half8*)(bb + kk * 16);
            acc0 = __builtin_amdgcn_mfma_f32_32x32x16_f16(a0, b0, acc0, 0, 0, 0);
            half8 a1 = *(const half8*)(ab + (size_t)(kk + 1) * CHW);
            half8 b1 = *(const half8*)(bb + (kk + 1) * 16);
            acc1 = __builtin_amdgcn_mfma_f32_32x32x16_f16(a1, b1, acc1, 0, 0, 0);
        }
        const int o = nt * 32 + (lane & 31);
        const float bias = fc_b[o];
        #pragma unroll
        for (int r = 0; r < 16; ++r) {
            const int m = (r & 3) + ((r >> 2) << 3) + ((lane >> 5) << 2);
            out[(size_t)m * (T_STEPS * OUT_DIM) + (size_t)t * OUT_DIM + o]
                = acc0[r] + acc1[r] + bias;
        }
    }
}

// ---- pre-cast x (-> [t][chunk16][b][16] fp16) and fc_w (-> fp16) ----
__global__ __launch_bounds__(256) void precast(
    const float* __restrict__ x, const float* __restrict__ fcw,
    _Float16* __restrict__ xb, _Float16* __restrict__ fcwb)
{
    const int idx = blockIdx.x * 256 + threadIdx.x;
    const int N1 = T_STEPS * BATCH * IN_DIM / 4;
    const int N2 = OUT_DIM * HID / 4;
    if (idx < N1) {
        int e = idx << 2;
        int d = e & (IN_DIM - 1);
        int bt = e >> 8;
        int b = bt & 31;
        int t = bt >> 5;
        float4 v = *(const float4*)(x + ((size_t)b * T_STEPS + t) * IN_DIM + d);
        _Float16* dst = xb + (((size_t)t * 16 + (d >> 4)) * 32 + b) * 16 + (d & 15);
        dst[0] = (_Float16)v.x; dst[1] = (_Float16)v.y;
        dst[2] = (_Float16)v.z; dst[3] = (_Float16)v.w;
    } else if (idx < N1 + N2) {
        int e = (idx - N1) << 2;
        float4 v = *(const float4*)(fcw + e);
        _Float16* dst = fcwb + e;
        dst[0] = (_Float16)v.x; dst[1] = (_Float16)v.y;
        dst[2] = (_Float16)v.z; dst[3] = (_Float16)v.w;
    }
}

extern "C" void kernel_launch(void* const* d_in, const int* in_sizes, int n_in,
                              void* d_out, int out_size, void* d_ws, size_t ws_size,
                              hipStream_t stream) {
    const float* x     = (const float*)d_in[0];
    const float* W_ih0 = (const float*)d_in[1];
    const float* W_hh0 = (const float*)d_in[2];
    const float* b_ih0 = (const float*)d_in[3];
    const float* b_hh0 = (const float*)d_in[4];
    const float* W_ih1 = (const float*)d_in[5];
    const float* W_hh1 = (const float*)d_in[6];
    const float* b_ih1 = (const float*)d_in[7];
    const float* b_hh1 = (const float*)d_in[8];
    const float* fc_w  = (const float*)d_in[9];
    const float* fc_b  = (const float*)d_in[10];
    float* out = (float*)d_out;

    char* ws = (char*)d_ws;
    size_t off = 0;
    _Float16* xb   = (_Float16*)(ws + off); off += (size_t)T_STEPS * BATCH * IN_DIM * 2;
    _Float16* h0a  = (_Float16*)(ws + off); off += (size_t)513 * SLOTE * 2;
    _Float16* h1a  = (_Float16*)(ws + off); off += (size_t)515 * SLOTE * 2;
    _Float16* fcwb = (_Float16*)(ws + off); off += (size_t)OUT_DIM * HID * 2;
    // total ws use ~76 MB

    hipMemsetAsync(h0a, 0x7E, (size_t)513 * SLOTE * 2, stream);
    hipMemsetAsync(h1a, 0x7E, (size_t)515 * SLOTE * 2, stream);
    hipMemsetAsync(h0a, 0, (size_t)SLOTE * 2, stream);              // h0 slot 0
    hipMemsetAsync(h1a + 2 * (size_t)SLOTE, 0, (size_t)SLOTE * 2, stream); // h1 slot 2
    precast<<<4352, 256, 0, stream>>>(x, fc_w, xb, fcwb);
    lstm_persist<<<128, TPB, 0, stream>>>(W_ih0, W_hh0, b_ih0, b_hh0,
                                          W_ih1, W_hh1, b_ih1, b_hh1,
                                          xb, h0a, h1a);
    fc_kern<<<128, 256, 0, stream>>>(h1a, fcwb, fc_b, out);
}

// Round 10
// 1950.680 us; speedup vs baseline: 2.0647x; 1.1396x over previous
//
#include <hip/hip_runtime.h>
#include <string.h>

// LSTM_13159779795583 : 2-layer LSTM (B=32,T=512,IN=256,H=1024) + FC(1024->256)
//
// Round 10: cacheable h broadcast with NaN-sentinel validation (ordering-free).
//  R9's seal protocol failed (absmax 0.18): payload-ack != L3-visibility, so
//  seal could land before payload -> stale cacheable fills. This round keeps
//  cacheable payload reads but guards them the R7-proven way:
//  - h slots NaN-prefilled (0x7E7E); |h|<1 so NaN is unreachable.
//  - producers: fire-and-forget 4B WT stores (no drain, no seal).
//  - hh consumers: sc0sc1 probe gate (16 chunks x 4 producer-wave samples),
//    then PLAIN CACHEABLE loads validated inline per-dword while MFMA-ing;
//    any NaN -> reset acc, redo whole K-slice via sc0sc1 spin (rare).
//  - xw1: same validate+fallback fast path (one-iteration slack, no probe).
//  - correctness rests only on 4B store atomicity + NaN sentinel, never on
//    store ordering or cache state -> G16-safe on any XCD.
//  - structure = R7 (layer-split WGs, publish-at-head, stage dbuf,
//    one __syncthreads/iter); cst padded [32][17].

#define T_STEPS 512
#define BATCH   32
#define IN_DIM  256
#define HID     1024
#define OUT_DIM 256
#define NWGL    64              // WGs per layer
#define TPB     512
#define U       16              // hidden units per WG
#define CHW     (BATCH * U)     // fp16 per chunk (512 = 1KB)
#define SLOTE   (NWGL * CHW)    // fp16 per slot (32768 = 64KB)
#define NITER   515             // i = 0..514

typedef _Float16 half8  __attribute__((ext_vector_type(8)));
typedef float    f32x16 __attribute__((ext_vector_type(16)));
typedef int      v4i    __attribute__((ext_vector_type(4)));

__device__ __forceinline__ float sigm(float x)      { return 1.f / (1.f + __expf(-x)); }
__device__ __forceinline__ float tanh_fast(float x) { return 2.f / (1.f + __expf(-2.f * x)) - 1.f; }

#define ATOMIC_ST4(p, v) __hip_atomic_store((p), (v), __ATOMIC_RELAXED, __HIP_MEMORY_SCOPE_AGENT)

// coherent 4B probe (bypass L1/L2); memory clobber = compiler barrier so the
// cacheable payload loads below cannot be hoisted above the gate
__device__ __forceinline__ unsigned probe4(const char* p) {
    unsigned v;
    asm volatile("global_load_dword %0, %1, off sc0 sc1\n\t"
                 "s_waitcnt vmcnt(0)" : "=v"(v) : "v"(p) : "memory");
    return v;
}

// 8 coherent 16B loads (chunk stride 1024B), one vmcnt(0)
__device__ __forceinline__ void ld8_coherent(const char* b0, v4i* F) {
    asm volatile(
        "global_load_dwordx4 %0, %8, off sc0 sc1\n\t"
        "global_load_dwordx4 %1, %8, off offset:1024 sc0 sc1\n\t"
        "global_load_dwordx4 %2, %8, off offset:2048 sc0 sc1\n\t"
        "global_load_dwordx4 %3, %8, off offset:3072 sc0 sc1\n\t"
        "global_load_dwordx4 %4, %9, off sc0 sc1\n\t"
        "global_load_dwordx4 %5, %9, off offset:1024 sc0 sc1\n\t"
        "global_load_dwordx4 %6, %9, off offset:2048 sc0 sc1\n\t"
        "global_load_dwordx4 %7, %9, off offset:3072 sc0 sc1\n\t"
        "s_waitcnt vmcnt(0)"
        : "=&v"(F[0]), "=&v"(F[1]), "=&v"(F[2]), "=&v"(F[3]),
          "=&v"(F[4]), "=&v"(F[5]), "=&v"(F[6]), "=&v"(F[7])
        : "v"(b0), "v"(b0 + 4096)
        : "memory");
}

// producers store 4B units; check low u16 of every dword
__device__ __forceinline__ bool frag_ok4(v4i f) {
    return ((f.x & 0xffff) != 0x7E7E) & ((f.y & 0xffff) != 0x7E7E)
         & ((f.z & 0xffff) != 0x7E7E) & ((f.w & 0xffff) != 0x7E7E);
}

__global__ __launch_bounds__(TPB, 2) void lstm_persist(
    const float* __restrict__ W_ih0, const float* __restrict__ W_hh0,
    const float* __restrict__ b_ih0, const float* __restrict__ b_hh0,
    const float* __restrict__ W_ih1, const float* __restrict__ W_hh1,
    const float* __restrict__ b_ih1, const float* __restrict__ b_hh1,
    const _Float16* __restrict__ xb,
    _Float16* __restrict__ h0a, _Float16* __restrict__ h1a)
{
    __shared__ float stage[2][8][BATCH][65];  // [buf][wave][b][n 0..63 +pad]
    __shared__ float cst[BATCH][17];          // cell state (padded; 16 used)
    __shared__ float biasS[64];               // b_ih+b_hh, 64 gate rows

    const int tid  = threadIdx.x;
    const int w    = tid >> 6;
    const int lane = tid & 63;
    const int rho  = lane & 31;
    const int kg   = (lane >> 5) << 3;   // 0 or 8
    const int blk  = blockIdx.x;
    const int isL1 = blk >= NWGL;
    const int be   = blk & (NWGL - 1);
    const bool isHH = (w < 4);

    const float* wptr; int kbase, nf, rowlen;
    if (isHH)      { wptr = isL1 ? W_hh1 : W_hh0; kbase = w * 256;       nf = 16; rowlen = HID;    }
    else if (isL1) { wptr = W_ih1;                kbase = (w - 4) * 256; nf = 16; rowlen = HID;    }
    else           { wptr = W_ih0;                kbase = (w - 4) * 64;  nf = 4;  rowlen = IN_DIM; }

    // ---- B fragments (fp32 -> fp16), once. Bf[kf][nh], nn = nh*32+rho ----
    half8 Bf[16][2];
    #pragma unroll
    for (int kf = 0; kf < 16; ++kf)
        #pragma unroll
        for (int nh = 0; nh < 2; ++nh) {
            half8 bf;
            if (kf < nf) {
                const int nn = nh * 32 + rho;
                const int row = (nn >> 4) * HID + be * U + (nn & 15);
                const float* p = wptr + (size_t)row * rowlen + kbase + kf * 16 + kg;
                float4 lo = *(const float4*)p;
                float4 hi = *(const float4*)(p + 4);
                bf[0] = (_Float16)lo.x; bf[1] = (_Float16)lo.y;
                bf[2] = (_Float16)lo.z; bf[3] = (_Float16)lo.w;
                bf[4] = (_Float16)hi.x; bf[5] = (_Float16)hi.y;
                bf[6] = (_Float16)hi.z; bf[7] = (_Float16)hi.w;
            } else {
                #pragma unroll
                for (int j = 0; j < 8; ++j) bf[j] = (_Float16)0.f;
            }
            Bf[kf][nh] = bf;
        }

    // ---- init ----
    if (tid < 64) {
        const int row = (tid >> 4) * HID + be * U + (tid & 15);
        biasS[tid] = isL1 ? (b_ih1[row] + b_hh1[row]) : (b_ih0[row] + b_hh0[row]);
    }
    if (tid < 512) cst[tid >> 4][tid & 15] = 0.f;
    __syncthreads();

    _Float16* hout = isL1 ? h1a : h0a;
    const _Float16* hself = hout;

    // ---- cell at head: compute h for slot, fire-and-forget WT store ----
    auto docell = [&](int slot, int sbp) {
        const int cid = w * 128 + lane * 2;
        const int b = cid >> 4, u0 = cid & 15;
        _Float16 h2[2];
        #pragma unroll
        for (int j = 0; j < 2; ++j) {
            const int u = u0 + j;
            float pre[4];
            #pragma unroll
            for (int g = 0; g < 4; ++g) {
                const int n = g * 16 + u;
                float v = biasS[n];
                #pragma unroll
                for (int p = 0; p < 8; ++p) v += stage[sbp][p][b][n];
                pre[g] = v;
            }
            float iv = sigm(pre[0]);
            float fv = sigm(pre[1]);
            float gv = tanh_fast(pre[2]);
            float ov = sigm(pre[3]);
            float c  = fv * cst[b][u] + iv * gv;
            cst[b][u] = c;
            h2[j] = (_Float16)(ov * tanh_fast(c));
        }
        unsigned pk; memcpy(&pk, h2, 4);
        ATOMIC_ST4((unsigned*)(hout + (size_t)slot * SLOTE + be * CHW + b * U + u0), pk);
    };

    #pragma unroll 1
    for (int i = 0; i < NITER; ++i) {
        const int sb = i & 1;

        const bool cell_act = isL1 ? (i >= 3 && i <= 514) : (i >= 1 && i <= 512);
        if (isHH && cell_act) docell(i, (i - 1) & 1);

        const bool comp_act = isL1 ? (i >= 2 && i < 2 + T_STEPS) : (i < T_STEPS);
        if (comp_act) {
            f32x16 acc0, acc1;
            #pragma unroll
            for (int r = 0; r < 16; ++r) { acc0[r] = 0.f; acc1[r] = 0.f; }

            if (isHH || isL1) {
                // payload base: hh reads own layer slot i; xw1 reads h0 slot i-1
                const _Float16* slotb;
                const int cw = isHH ? w : (w - 4);
                if (isHH) slotb = hself + (size_t)i * SLOTE;
                else      slotb = h0a + (size_t)(i - 1) * SLOTE;

                if (isHH) {
                    // probe gate: 16 chunks x 4 producer-wave samples
                    const char* pp = (const char*)slotb
                        + (size_t)(cw * 16 + (lane & 15)) * 1024 + (lane >> 4) * 8;
                    while (!__all((probe4(pp) & 0xffffu) != 0x7E7Eu)) {}
                }

                const _Float16* ap = slotb + (size_t)(cw * 16) * CHW + rho * U + kg;
                // fast path: cacheable loads, validate inline while MFMA-ing
                bool ok = true;
                #pragma unroll
                for (int j = 0; j < 16; ++j) {
                    v4i f = *(const v4i*)(ap + (size_t)j * CHW);
                    ok &= frag_ok4(f);
                    half8 a = __builtin_bit_cast(half8, f);
                    acc0 = __builtin_amdgcn_mfma_f32_32x32x16_f16(a, Bf[j][0], acc0, 0, 0, 0);
                    acc1 = __builtin_amdgcn_mfma_f32_32x32x16_f16(a, Bf[j][1], acc1, 0, 0, 0);
                }
                if (!__all(ok)) {
                    // rare straggler: discard and redo coherently (R7-proven)
                    #pragma unroll
                    for (int r = 0; r < 16; ++r) { acc0[r] = 0.f; acc1[r] = 0.f; }
                    #pragma unroll
                    for (int g = 0; g < 2; ++g) {
                        v4i F[8];
                        for (;;) {
                            ld8_coherent((const char*)(ap + (size_t)g * 8 * CHW), F);
                            bool ok2 = true;
                            #pragma unroll
                            for (int j = 0; j < 8; ++j) ok2 &= frag_ok4(F[j]);
                            if (__all(ok2)) break;
                            __builtin_amdgcn_s_sleep(1);
                        }
                        #pragma unroll
                        for (int j = 0; j < 8; ++j) {
                            half8 a = __builtin_bit_cast(half8, F[j]);
                            acc0 = __builtin_amdgcn_mfma_f32_32x32x16_f16(a, Bf[g * 8 + j][0], acc0, 0, 0, 0);
                            acc1 = __builtin_amdgcn_mfma_f32_32x32x16_f16(a, Bf[g * 8 + j][1], acc1, 0, 0, 0);
                        }
                    }
                }
            } else {
                // xw0: static x, 4 frags
                const _Float16* ap = xb + ((size_t)i * 16 + (w - 4) * 4) * CHW + rho * U + kg;
                #pragma unroll
                for (int j = 0; j < 4; ++j) {
                    half8 a = *(const half8*)(ap + (size_t)j * CHW);
                    acc0 = __builtin_amdgcn_mfma_f32_32x32x16_f16(a, Bf[j][0], acc0, 0, 0, 0);
                    acc1 = __builtin_amdgcn_mfma_f32_32x32x16_f16(a, Bf[j][1], acc1, 0, 0, 0);
                }
            }
            // C/D: n = lane&31, b = (r&3)+8*(r>>2)+4*(lane>>5)
            #pragma unroll
            for (int r = 0; r < 16; ++r) {
                const int b = (r & 3) + ((r >> 2) << 3) + ((lane >> 5) << 2);
                stage[sb][w][b][rho]      = acc0[r];
                stage[sb][w][b][32 + rho] = acc1[r];
            }
        }
        __syncthreads();
    }
}

// ---- epilogue FC: h1[t] = slot t+3, layout [slot][wg][b][u16] ----
__global__ __launch_bounds__(256) void fc_kern(
    const _Float16* __restrict__ h1a, const _Float16* __restrict__ fcwb,
    const float* __restrict__ fc_b, float* __restrict__ out)
{
    const int wv   = threadIdx.x >> 6;
    const int lane = threadIdx.x & 63;
    const int t    = blockIdx.x * 4 + wv;
    const int kg   = (lane >> 5) << 3;
    const _Float16* ab = h1a + (size_t)(t + 3) * SLOTE + (size_t)(lane & 31) * U + kg;

    #pragma unroll 1
    for (int nt = 0; nt < 8; ++nt) {
        const _Float16* bb = fcwb + (size_t)(nt * 32 + (lane & 31)) * HID + kg;
        f32x16 acc0, acc1;
        #pragma unroll
        for (int r = 0; r < 16; ++r) { acc0[r] = 0.f; acc1[r] = 0.f; }
        #pragma unroll
        for (int kk = 0; kk < 64; kk += 2) {
            half8 a0 = *(const half8*)(ab + (size_t)kk * CHW);
            half8 b0 = *(const half8*)(bb + kk * 16);
            acc0 = __builtin_amdgcn_mfma_f32_32x32x16_f16(a0, b0, acc0, 0, 0, 0);
            half8 a1 = *(const half8*)(ab + (size_t)(kk + 1) * CHW);
            half8 b1 = *(const half8*)(bb + (kk + 1) * 16);
            acc1 = __builtin_amdgcn_mfma_f32_32x32x16_f16(a1, b1, acc1, 0, 0, 0);
        }
        const int o = nt * 32 + (lane & 31);
        const float bias = fc_b[o];
        #pragma unroll
        for (int r = 0; r < 16; ++r) {
            const int m = (r & 3) + ((r >> 2) << 3) + ((lane >> 5) << 2);
            out[(size_t)m * (T_STEPS * OUT_DIM) + (size_t)t * OUT_DIM + o]
                = acc0[r] + acc1[r] + bias;
        }
    }
}

// ---- pre-cast x (-> [t][chunk16][b][16] fp16) and fc_w (-> fp16) ----
__global__ __launch_bounds__(256) void precast(
    const float* __restrict__ x, const float* __restrict__ fcw,
    _Float16* __restrict__ xb, _Float16* __restrict__ fcwb)
{
    const int idx = blockIdx.x * 256 + threadIdx.x;
    const int N1 = T_STEPS * BATCH * IN_DIM / 4;
    const int N2 = OUT_DIM * HID / 4;
    if (idx < N1) {
        int e = idx << 2;
        int d = e & (IN_DIM - 1);
        int bt = e >> 8;
        int b = bt & 31;
        int t = bt >> 5;
        float4 v = *(const float4*)(x + ((size_t)b * T_STEPS + t) * IN_DIM + d);
        _Float16* dst = xb + (((size_t)t * 16 + (d >> 4)) * 32 + b) * 16 + (d & 15);
        dst[0] = (_Float16)v.x; dst[1] = (_Float16)v.y;
        dst[2] = (_Float16)v.z; dst[3] = (_Float16)v.w;
    } else if (idx < N1 + N2) {
        int e = (idx - N1) << 2;
        float4 v = *(const float4*)(fcw + e);
        _Float16* dst = fcwb + e;
        dst[0] = (_Float16)v.x; dst[1] = (_Float16)v.y;
        dst[2] = (_Float16)v.z; dst[3] = (_Float16)v.w;
    }
}

extern "C" void kernel_launch(void* const* d_in, const int* in_sizes, int n_in,
                              void* d_out, int out_size, void* d_ws, size_t ws_size,
                              hipStream_t stream) {
    const float* x     = (const float*)d_in[0];
    const float* W_ih0 = (const float*)d_in[1];
    const float* W_hh0 = (const float*)d_in[2];
    const float* b_ih0 = (const float*)d_in[3];
    const float* b_hh0 = (const float*)d_in[4];
    const float* W_ih1 = (const float*)d_in[5];
    const float* W_hh1 = (const float*)d_in[6];
    const float* b_ih1 = (const float*)d_in[7];
    const float* b_hh1 = (const float*)d_in[8];
    const float* fc_w  = (const float*)d_in[9];
    const float* fc_b  = (const float*)d_in[10];
    float* out = (float*)d_out;

    char* ws = (char*)d_ws;
    size_t off = 0;
    _Float16* xb   = (_Float16*)(ws + off); off += (size_t)T_STEPS * BATCH * IN_DIM * 2;
    _Float16* h0a  = (_Float16*)(ws + off); off += (size_t)513 * SLOTE * 2;
    _Float16* h1a  = (_Float16*)(ws + off); off += (size_t)515 * SLOTE * 2;
    _Float16* fcwb = (_Float16*)(ws + off); off += (size_t)OUT_DIM * HID * 2;
    // total ws use ~74.5 MB

    // NaN-sentinel prefill, then zero the initial-state slots
    hipMemsetAsync(h0a, 0x7E, (size_t)513 * SLOTE * 2, stream);
    hipMemsetAsync(h1a, 0x7E, (size_t)515 * SLOTE * 2, stream);
    hipMemsetAsync(h0a, 0, (size_t)SLOTE * 2, stream);                      // h0 slot 0
    hipMemsetAsync(h1a + (size_t)2 * SLOTE, 0, (size_t)SLOTE * 2, stream);  // h1 slot 2
    precast<<<4352, 256, 0, stream>>>(x, fc_w, xb, fcwb);
    lstm_persist<<<128, TPB, 0, stream>>>(W_ih0, W_hh0, b_ih0, b_hh0,
                                          W_ih1, W_hh1, b_ih1, b_hh1,
                                          xb, h0a, h1a);
    fc_kern<<<128, 256, 0, stream>>>(h1a, fcwb, fc_b, out);
}